// Round 1
// baseline (182.296 us; speedup 1.0000x reference)
//
#include <hip/hip_runtime.h>
#include <math.h>

#define KBINS 8192
#define DDIM  16384      // 2*K
#define HID   2048
#define NROWS1 16385     // D+1

#define CHUNK1 64
#define R1 257           // ceil(16385/64)
#define CHUNK2 64
#define R2 32            // 2048/64

static constexpr float SQRT2_F = 1.4142135623730951f;

// ---------------- Kernel A: partial matvec1  (inp @ W1) ----------------
// grid (2, R1), block 256. Each thread owns 4 consecutive cols (float4 loads).
__global__ void mv1_partial(const float* __restrict__ mu, const float* __restrict__ t,
                            const float* __restrict__ W1, float* __restrict__ part) {
    int c0 = (blockIdx.x * 256 + threadIdx.x) * 4;   // 0..2044
    int r0 = blockIdx.y * CHUNK1;
    int r1 = r0 + CHUNK1; if (r1 > NROWS1) r1 = NROWS1;
    float4 acc = {0.f, 0.f, 0.f, 0.f};
    for (int r = r0; r < r1; ++r) {
        float a = (r < DDIM) ? mu[r] : t[0];
        const float4 w = *reinterpret_cast<const float4*>(W1 + (size_t)r * HID + c0);
        acc.x += a * w.x; acc.y += a * w.y; acc.z += a * w.z; acc.w += a * w.w;
    }
    *reinterpret_cast<float4*>(part + (size_t)blockIdx.y * HID + c0) = acc;
}

// ---------------- Kernel B: reduce partials + bias + leaky_relu ----------------
// grid 8, block 256 (2048 cols)
__global__ void mv1_reduce(const float* __restrict__ part, const float* __restrict__ b1,
                           float* __restrict__ h) {
    int c = blockIdx.x * 256 + threadIdx.x;
    float s = b1[c];
    for (int rb = 0; rb < R1; ++rb) s += part[(size_t)rb * HID + c];
    h[c] = (s >= 0.f) ? s : 0.01f * s;
}

// ---------------- Kernel C: partial matvec2  (h @ W2) ----------------
// grid (16, R2), block 256.
__global__ void mv2_partial(const float* __restrict__ h, const float* __restrict__ W2,
                            float* __restrict__ part) {
    int c0 = (blockIdx.x * 256 + threadIdx.x) * 4;   // 0..16380
    int r0 = blockIdx.y * CHUNK2;
    int r1 = r0 + CHUNK2;
    float4 acc = {0.f, 0.f, 0.f, 0.f};
    for (int r = r0; r < r1; ++r) {
        float a = h[r];
        const float4 w = *reinterpret_cast<const float4*>(W2 + (size_t)r * DDIM + c0);
        acc.x += a * w.x; acc.y += a * w.y; acc.z += a * w.z; acc.w += a * w.w;
    }
    *reinterpret_cast<float4*>(part + (size_t)blockIdx.y * DDIM + c0) = acc;
}

// ---------------- Kernel D: reduce + bias + postprocess -> mu_x, sigma_x ----------------
// grid 32, block 256 (8192 rows)
__global__ void postproc(const float* __restrict__ part, const float* __restrict__ b2,
                         const float* __restrict__ mu, const float* __restrict__ t,
                         const float* __restrict__ gamma,
                         float* __restrict__ mu_x, float* __restrict__ sigma_x) {
    int i = blockIdx.x * 256 + threadIdx.x;
    float s0 = b2[i];            // mu_eps accumulator
    float s1 = b2[i + KBINS];    // ln_sig accumulator
    for (int rb = 0; rb < R2; ++rb) {
        s0 += part[(size_t)rb * DDIM + i];
        s1 += part[(size_t)rb * DDIM + i + KBINS];
    }
    float g  = gamma[0];
    float pe = 1.0f / (1.0f - g);
    float pm = g - pe;
    bool use_nn = (t[0] >= 1e-10f);
    float mx = powf(mu[i], pm) * powf(s0, pe);
    float sx = powf(1.0f - g, -0.5f) * expf(0.5f * s1);
    mu_x[i]    = use_nn ? mx : 0.0f;
    sigma_x[i] = use_nn ? sx : 1.0f;
}

// ---------------- Kernel E: out[i][j] = F_i(kr[j]) - F_i(kl[j]) ----------------
// grid (8, 8192), block 256. Each thread -> 4 consecutive j (float4 store).
// kl[j] = 2(j-1)/(K-1) = kr[j-1]; share boundary F values: 5 erfs per 4 outputs.
// For j0 > 4096 the whole float4 is exactly zero (both CDFs clamp to 1).
__global__ void cdf_diff(const float* __restrict__ mu_x, const float* __restrict__ sigma_x,
                         float* __restrict__ out) {
    int i  = blockIdx.y;
    int j0 = (blockIdx.x * 256 + threadIdx.x) * 4;
    float4 r;
    if (j0 > 4096) {
        r.x = r.y = r.z = r.w = 0.f;
    } else {
        float m   = mu_x[i];
        float inv = 1.0f / (sigma_x[i] * SQRT2_F);
        const float sc = 2.0f / 8191.0f;
        float F[5];
#pragma unroll
        for (int k = 0; k < 5; ++k) {
            float x = (float)(j0 - 1 + k) * sc;
            float f;
            if (x >= 1.0f)       f = 1.0f;
            else if (x <= -1.0f) f = 0.0f;
            else                 f = 0.5f * (1.0f + erff((x - m) * inv));
            F[k] = f;
        }
        r.x = F[1] - F[0]; r.y = F[2] - F[1]; r.z = F[3] - F[2]; r.w = F[4] - F[3];
    }
    *reinterpret_cast<float4*>(out + (size_t)i * KBINS + j0) = r;
}

extern "C" void kernel_launch(void* const* d_in, const int* in_sizes, int n_in,
                              void* d_out, int out_size, void* d_ws, size_t ws_size,
                              hipStream_t stream) {
    const float* mu    = (const float*)d_in[0];
    const float* t     = (const float*)d_in[1];
    const float* gamma = (const float*)d_in[2];
    const float* W1    = (const float*)d_in[3];
    const float* b1    = (const float*)d_in[4];
    const float* W2    = (const float*)d_in[5];
    const float* b2    = (const float*)d_in[6];
    float* out = (float*)d_out;

    float* ws      = (float*)d_ws;
    float* part1   = ws;                          // R1*HID   = 526336 floats
    float* h       = part1 + (size_t)R1 * HID;    // 2048
    float* part2   = h + HID;                     // R2*DDIM  = 524288
    float* mu_x    = part2 + (size_t)R2 * DDIM;   // 8192
    float* sigma_x = mu_x + KBINS;                // 8192
    // total ~1.07M floats = ~4.3 MB of ws

    mv1_partial<<<dim3(2, R1),  dim3(256), 0, stream>>>(mu, t, W1, part1);
    mv1_reduce <<<dim3(8),      dim3(256), 0, stream>>>(part1, b1, h);
    mv2_partial<<<dim3(16, R2), dim3(256), 0, stream>>>(h, W2, part2);
    postproc   <<<dim3(32),     dim3(256), 0, stream>>>(part2, b2, mu, t, gamma, mu_x, sigma_x);
    cdf_diff   <<<dim3(8, 8192),dim3(256), 0, stream>>>(mu_x, sigma_x, out);
}

// Round 2
// 165.186 us; speedup vs baseline: 1.1036x; 1.1036x over previous
//
#include <hip/hip_runtime.h>
#include <math.h>

#define KBINS 8192
#define DDIM  16384      // 2*K
#define HID   2048
#define NROWS1 16385     // D+1

#define C1 32
#define R1P 513          // ceil(16385/32)
#define C2 32
#define R2P 64           // 2048/32

static constexpr float SQRT2_F = 1.4142135623730951f;

// Branch-free erf approximation (Abramowitz-Stegun 7.1.26), |err| < 1.5e-7.
__device__ __forceinline__ float fast_erff(float x) {
    float ax = fabsf(x);
    float t  = 1.0f / fmaf(0.3275911f, ax, 1.0f);
    float p  = t * (0.254829592f +
               t * (-0.284496736f +
               t * (1.421413741f +
               t * (-1.453152027f +
               t * 1.061405429f))));
    float r = 1.0f - p * __expf(-ax * ax);
    return copysignf(r, x);
}

// ---------------- K1: partial matvec1  (inp @ W1), split-K ----------------
// grid (2, 513), block 256. Thread owns 4 consecutive cols (float4 loads).
__global__ void __launch_bounds__(256)
mv1_partial(const float* __restrict__ mu, const float* __restrict__ t,
            const float* __restrict__ W1, float* __restrict__ part) {
    __shared__ float a_s[C1];
    int r0 = blockIdx.y * C1;
    int nr = NROWS1 - r0; if (nr > C1) nr = C1;
    if (threadIdx.x < C1) {
        int r = r0 + threadIdx.x;
        float a = 0.f;
        if (threadIdx.x < nr) a = (r < DDIM) ? mu[r] : t[0];
        a_s[threadIdx.x] = a;
    }
    __syncthreads();
    int c0 = (blockIdx.x * 256 + threadIdx.x) * 4;   // 0..2044
    float4 acc = {0.f, 0.f, 0.f, 0.f};
    for (int k = 0; k < nr; ++k) {
        float a = a_s[k];
        const float4 w = *reinterpret_cast<const float4*>(W1 + (size_t)(r0 + k) * HID + c0);
        acc.x += a * w.x; acc.y += a * w.y; acc.z += a * w.z; acc.w += a * w.w;
    }
    *reinterpret_cast<float4*>(part + (size_t)blockIdx.y * HID + c0) = acc;
}

// ---------------- K2: fused (reduce part1 -> h chunk) + partial matvec2 ----------------
// grid (16, 64), block 256. Each block rebuilds its 32 h values from part1
// (fixed-order strided sums -> deterministic, identical across bx), then streams W2.
__global__ void __launch_bounds__(256)
mv2_fused(const float* __restrict__ part1, const float* __restrict__ b1,
          const float* __restrict__ W2, float* __restrict__ part2) {
    __shared__ float red[8][C1];
    __shared__ float hs[C1];
    int r0 = blockIdx.y * C2;
    int part = threadIdx.x >> 5;    // 0..7
    int hidx = threadIdx.x & 31;    // 0..31
    float s = 0.f;
    for (int rb = part; rb < R1P; rb += 8)
        s += part1[(size_t)rb * HID + r0 + hidx];
    red[part][hidx] = s;
    __syncthreads();
    if (threadIdx.x < C1) {
        float v = b1[r0 + threadIdx.x];
        for (int p = 0; p < 8; ++p) v += red[p][threadIdx.x];
        hs[threadIdx.x] = (v >= 0.f) ? v : 0.01f * v;   // leaky relu
    }
    __syncthreads();
    int c0 = (blockIdx.x * 256 + threadIdx.x) * 4;   // 0..16380
    float4 acc = {0.f, 0.f, 0.f, 0.f};
    for (int k = 0; k < C2; ++k) {
        float a = hs[k];
        const float4 w = *reinterpret_cast<const float4*>(W2 + (size_t)(r0 + k) * DDIM + c0);
        acc.x += a * w.x; acc.y += a * w.y; acc.z += a * w.z; acc.w += a * w.w;
    }
    *reinterpret_cast<float4*>(part2 + (size_t)blockIdx.y * DDIM + c0) = acc;
}

// ---------------- K3: fused (reduce part2 -> mu_x, sigma_x) + CDF-diff row ----------------
// grid (8192), block 256; one block per output row i.
__global__ void __launch_bounds__(256)
cdf_fused(const float* __restrict__ part2, const float* __restrict__ b2,
          const float* __restrict__ mu, const float* __restrict__ t,
          const float* __restrict__ gamma, float* __restrict__ out) {
    int i   = blockIdx.x;
    int tid = threadIdx.x;
    __shared__ float sh[2];
    if (tid < 128) {
        int which = tid >> 6;          // 0 -> mu_eps (col i), 1 -> ln_sig (col i+K)
        int lane  = tid & 63;          // = rb
        float v = part2[(size_t)lane * DDIM + i + which * KBINS];
        for (int off = 32; off; off >>= 1) v += __shfl_xor(v, off, 64);
        if (lane == 0) sh[which] = v + b2[i + which * KBINS];
    }
    __syncthreads();
    float g  = gamma[0];
    float pe = 1.0f / (1.0f - g);
    float pm = g - pe;
    bool use_nn = (t[0] >= 1e-10f);
    float s0 = sh[0], s1 = sh[1];
    float m   = use_nn ? powf(mu[i], pm) * powf(s0, pe)       : 0.0f;
    float sx  = use_nn ? powf(1.0f - g, -0.5f) * expf(0.5f * s1) : 1.0f;
    float inv = 1.0f / (sx * SQRT2_F);
    const float sc = 2.0f / 8191.0f;

    float* orow = out + (size_t)i * KBINS;
#pragma unroll
    for (int it = 0; it < 8; ++it) {
        int j0 = it * 1024 + tid * 4;
        float4 r;
        if (j0 > 4096) {
            r.x = r.y = r.z = r.w = 0.f;   // both CDFs clamp to 1 for j >= 4097
        } else {
            float F[5];
#pragma unroll
            for (int k = 0; k < 5; ++k) {
                float x = (float)(j0 - 1 + k) * sc;
                float f;
                if (x >= 1.0f)       f = 1.0f;
                else if (x <= -1.0f) f = 0.0f;
                else                 f = 0.5f * (1.0f + fast_erff((x - m) * inv));
                F[k] = f;
            }
            r.x = F[1] - F[0]; r.y = F[2] - F[1]; r.z = F[3] - F[2]; r.w = F[4] - F[3];
        }
        *reinterpret_cast<float4*>(orow + j0) = r;
    }
}

extern "C" void kernel_launch(void* const* d_in, const int* in_sizes, int n_in,
                              void* d_out, int out_size, void* d_ws, size_t ws_size,
                              hipStream_t stream) {
    const float* mu    = (const float*)d_in[0];
    const float* t     = (const float*)d_in[1];
    const float* gamma = (const float*)d_in[2];
    const float* W1    = (const float*)d_in[3];
    const float* b1    = (const float*)d_in[4];
    const float* W2    = (const float*)d_in[5];
    const float* b2    = (const float*)d_in[6];
    float* out = (float*)d_out;

    float* ws    = (float*)d_ws;
    float* part1 = ws;                           // R1P*HID  = 1,050,624 floats (~4.2 MB)
    float* part2 = part1 + (size_t)R1P * HID;    // R2P*DDIM = 1,048,576 floats (~4.2 MB)

    mv1_partial<<<dim3(2, R1P),  dim3(256), 0, stream>>>(mu, t, W1, part1);
    mv2_fused  <<<dim3(16, R2P), dim3(256), 0, stream>>>(part1, b1, W2, part2);
    cdf_fused  <<<dim3(KBINS),   dim3(256), 0, stream>>>(part2, b2, mu, t, gamma, out);
}